// Round 10
// baseline (168.860 us; speedup 1.0000x reference)
//
#include <hip/hip_runtime.h>
#include <hip/hip_bf16.h>
#include <stdint.h>

// Problem constants (fixed by setup_inputs)
#define PRIME 2147483647u
#define GAMMA 0.3f
#define K_HASH 128
#define S_SET 8
#define NB 4
#define LQ 1024
#define LK 1024
#define EDIM 512

typedef unsigned short ushort_t;
typedef __attribute__((ext_vector_type(8))) short short8;
typedef __attribute__((ext_vector_type(4))) float f32x4;

static __device__ __forceinline__ unsigned short f2bf(float f) {
    unsigned u = __builtin_bit_cast(unsigned, f);
    u += 0x7FFFu + ((u >> 16) & 1u);   // RNE (no NaN in this problem)
    return (unsigned short)(u >> 16);
}

// async global->LDS, 16B per lane; LDS dst must be lane-contiguous.
static __device__ __forceinline__ void glds16(const void* g, void* l) {
    __builtin_amdgcn_global_load_lds(
        (const __attribute__((address_space(1))) unsigned int*)g,
        (__attribute__((address_space(3))) unsigned int*)l, 16, 0, 0);
}

#define SWZ(r) ((((r) >> 2) & 3) ^ ((r) & 3))

// packed nonmatch accumulate: acc += per-half min(a^b,1). Forced v_pk_min_u16
// (LLVM scalarizes __builtin_elementwise_min on u16x2: R5->R6 proved 2.1x).
static __device__ __forceinline__ unsigned nm2(unsigned acc, unsigned a,
                                               unsigned b, unsigned ones) {
    unsigned x = a ^ b, t;
    asm("v_pk_min_u16 %0, %1, %2" : "=v"(t) : "v"(x), "v"(ones));
    return acc + t;                       // halves <= 64: no cross-half carry
}
static __device__ __forceinline__ unsigned nm8(unsigned acc, int4 q, int4 k,
                                               unsigned ones) {
    acc = nm2(acc, (unsigned)q.x, (unsigned)k.x, ones);
    acc = nm2(acc, (unsigned)q.y, (unsigned)k.y, ones);
    acc = nm2(acc, (unsigned)q.z, (unsigned)k.z, ones);
    acc = nm2(acc, (unsigned)q.w, (unsigned)k.w, ones);
    return acc;
}

// ---------------------------------------------------------------------------
// 64x64-tile bf16 BT-GEMM: C[M,N] = A[M,K] @ B[N,K]^T (+epilogue), f32 accum,
// 4 waves x 32x32, glds width-16, XOR-swizzled LDS, double-buffered.
// ---------------------------------------------------------------------------
#define EPI_NONE     0     // bf16 out, no epilogue
#define EPI_DIVBIAS  1     // f32 out, v = v/scale[gm] + bias[gn]

template<int OUTF32, int MODE>
static __device__ void gemm64(
        const ushort_t* __restrict__ A, const ushort_t* __restrict__ B,
        void* __restrict__ C,
        const float* __restrict__ bias, const float* __restrict__ scale,
        int lda, int ldb, int ldc, int Kd, int m0, int n0,
        ushort_t* AsBase, ushort_t* BsBase, int tid) {
    ushort_t (*As)[64 * 32] = (ushort_t (*)[64 * 32])AsBase;
    ushort_t (*Bs)[64 * 32] = (ushort_t (*)[64 * 32])BsBase;
    int w = tid >> 6, lane = tid & 63;
    int wm = (w & 1) * 32, wn = (w >> 1) * 32;
    int mrow = lane & 15, kg = lane >> 4;

    int r = tid >> 2, c = (tid & 3) ^ SWZ(r);
    const ushort_t* pa = A + (size_t)(m0 + r) * lda + c * 8;
    const ushort_t* pb = B + (size_t)(n0 + r) * ldb + c * 8;

    int aoff[2], boff[2];
    #pragma unroll
    for (int s = 0; s < 2; s++) {
        int Ra = wm + s * 16 + mrow;
        aoff[s] = Ra * 32 + (kg ^ SWZ(Ra)) * 8;
        int Rb = wn + s * 16 + mrow;
        boff[s] = Rb * 32 + (kg ^ SWZ(Rb)) * 8;
    }

    f32x4 acc[2][2] = {};
    int nK = Kd >> 5;
    glds16(pa, &As[0][tid * 8]);
    glds16(pb, &Bs[0][tid * 8]);
    for (int i = 0; i < nK; i++) {
        __syncthreads();
        int cur = i & 1, nxt = cur ^ 1;
        if (i + 1 < nK) {
            int k0 = (i + 1) << 5;
            glds16(pa + k0, &As[nxt][tid * 8]);
            glds16(pb + k0, &Bs[nxt][tid * 8]);
        }
        short8 af[2], bh[2];
        #pragma unroll
        for (int s = 0; s < 2; s++) {
            af[s] = *(const short8*)&As[cur][aoff[s]];
            bh[s] = *(const short8*)&Bs[cur][boff[s]];
        }
        #pragma unroll
        for (int ii = 0; ii < 2; ii++)
            #pragma unroll
            for (int jj = 0; jj < 2; jj++)
                acc[ii][jj] = __builtin_amdgcn_mfma_f32_16x16x32_bf16(
                                  af[ii], bh[jj], acc[ii][jj], 0, 0, 0);
    }

    int col = lane & 15, rbase = (lane >> 4) * 4;
    #pragma unroll
    for (int ii = 0; ii < 2; ii++) {
        #pragma unroll
        for (int jj = 0; jj < 2; jj++) {
            #pragma unroll
            for (int rr = 0; rr < 4; rr++) {
                int gm = m0 + wm + ii * 16 + rbase + rr;
                int gn = n0 + wn + jj * 16 + col;
                float v = acc[ii][jj][rr];
                if (MODE == EPI_DIVBIAS) v = v / scale[gm] + bias[gn];
                size_t cix = (size_t)gm * ldc + gn;
                if (OUTF32) ((float*)C)[cix] = v;
                else        ((ushort_t*)C)[cix] = f2bf(v);
            }
        }
    }
}

// ---------------------------------------------------------------------------
// 1) prep: Wo convert, value/Wv TRANSPOSED convert (VbT[e,bj], WvT[e,m]),
//    signatures (low-16-bit truncated), bias2 = Wo@bv + bo, zero rs.
// ---------------------------------------------------------------------------
#define PREP_WO   128
#define PREP_TV   512
#define PREP_TW   64
#define PREP_SIG  1024
#define PREP_B2   2
#define PREP_BLOCKS (PREP_WO + PREP_TV + PREP_TW + PREP_SIG + PREP_B2)

union PrepSmem {
    ushort_t Ts[64][66];
    float bvs[512];
};

static __device__ void tconvert(const float* __restrict__ src,
                                ushort_t* __restrict__ dst,
                                int R, int C, int r0, int c0, int tid,
                                ushort_t (*Ts)[66]) {
    int rr = tid >> 2, c4 = (tid & 3) * 16;
    const float* s = src + (size_t)(r0 + rr) * C + c0 + c4;
    float4 a = *(const float4*)(s + 0), b = *(const float4*)(s + 4);
    float4 cc = *(const float4*)(s + 8), d = *(const float4*)(s + 12);
    ushort_t* tr = &Ts[rr][c4];
    tr[0]=f2bf(a.x);  tr[1]=f2bf(a.y);  tr[2]=f2bf(a.z);  tr[3]=f2bf(a.w);
    tr[4]=f2bf(b.x);  tr[5]=f2bf(b.y);  tr[6]=f2bf(b.z);  tr[7]=f2bf(b.w);
    tr[8]=f2bf(cc.x); tr[9]=f2bf(cc.y); tr[10]=f2bf(cc.z); tr[11]=f2bf(cc.w);
    tr[12]=f2bf(d.x); tr[13]=f2bf(d.y); tr[14]=f2bf(d.z); tr[15]=f2bf(d.w);
    __syncthreads();
    int er = tid >> 3, bc = (tid & 7) * 8;
    #pragma unroll
    for (int it = 0; it < 2; it++) {
        int e = er + it * 32;
        ushort_t tmp[8];
        #pragma unroll
        for (int i = 0; i < 8; i++) tmp[i] = Ts[bc + i][e];
        *(short8*)&dst[(size_t)(c0 + e) * R + r0 + bc] = *(const short8*)tmp;
    }
}

__global__ __launch_bounds__(256) void prep_kernel(
        const float* __restrict__ value, const float* __restrict__ wv,
        const float* __restrict__ wo,
        const float* __restrict__ bv, const float* __restrict__ bo,
        const int* __restrict__ tsq, const int* __restrict__ tsk,
        const int* __restrict__ ha, const int* __restrict__ hb,
        ushort_t* __restrict__ VbT, ushort_t* __restrict__ WvT,
        ushort_t* __restrict__ Wob,
        ushort_t* __restrict__ sigq, ushort_t* __restrict__ sigk,
        float* __restrict__ rs, float* __restrict__ bias2) {
    __shared__ PrepSmem sm;
    int blk = blockIdx.x, tid = threadIdx.x;
    if (blk < 16) rs[blk * 256 + tid] = 0.f;        // zero rowsum[4096]
    if (blk < PREP_WO) {                            // ---- Wo plain convert ----
        size_t i = ((size_t)blk * 256 + tid) * 8;
        float4 a = *(const float4*)(wo + i), b = *(const float4*)(wo + i + 4);
        ushort4 o0, o1;
        o0.x=f2bf(a.x); o0.y=f2bf(a.y); o0.z=f2bf(a.z); o0.w=f2bf(a.w);
        o1.x=f2bf(b.x); o1.y=f2bf(b.y); o1.z=f2bf(b.z); o1.w=f2bf(b.w);
        *(ushort4*)(Wob + i)     = o0;
        *(ushort4*)(Wob + i + 4) = o1;
        return;
    }
    if (blk < PREP_WO + PREP_TV) {                  // ---- value transpose ----
        int t = blk - PREP_WO;
        tconvert(value, VbT, NB * LK, EDIM, (t & 63) * 64, (t >> 6) * 64, tid, sm.Ts);
        return;
    }
    if (blk < PREP_WO + PREP_TV + PREP_TW) {        // ---- Wv transpose ----
        int t = blk - PREP_WO - PREP_TV;
        tconvert(wv, WvT, EDIM, EDIM, (t & 7) * 64, (t >> 3) * 64, tid, sm.Ts);
        return;
    }
    if (blk < PREP_WO + PREP_TV + PREP_TW + PREP_SIG) {   // ---- signatures ----
        int sb = blk - PREP_WO - PREP_TV - PREP_TW;
        int k = tid & 127, half = tid >> 7;
        unsigned long long a  = (unsigned)ha[k];
        unsigned long long bb = (unsigned)hb[k];
        #pragma unroll
        for (int p = 0; p < 4; p++) {
            int row = sb * 8 + p * 2 + half;        // 0..8191
            const int* ts = (row < NB * LQ) ? tsq : tsk;
            ushort_t* sig = (row < NB * LQ) ? sigq : sigk;
            int idx = row & (NB * LQ - 1);
            unsigned mn = 0xFFFFFFFFu;
            #pragma unroll
            for (int s = 0; s < S_SET; s++) {
                unsigned long long x =
                    a * (unsigned long long)(unsigned)ts[idx * S_SET + s] + bb;
                x = (x & PRIME) + (x >> 31);        // 2^31 == 1 (mod 2^31-1)
                x = (x & PRIME) + (x >> 31);
                unsigned r = (unsigned)x;
                if (r >= PRIME) r -= PRIME;
                mn = (r < mn) ? r : mn;
            }
            sig[idx * K_HASH + k] = (ushort_t)mn;
        }
        return;
    }
    // ---- bias2[n] = dot(Wo[n,:], bv) + bo[n] ----
    int sb2 = blk - (PREP_BLOCKS - PREP_B2);
    sm.bvs[tid] = bv[tid];
    sm.bvs[256 + tid] = bv[256 + tid];
    __syncthreads();
    int n = sb2 * 256 + tid;
    float acc = bo[n];
    #pragma unroll 8
    for (int e = 0; e < EDIM; e++) acc += wo[(size_t)n * EDIM + e] * sm.bvs[e];
    bias2[n] = acc;
}

// ---------------------------------------------------------------------------
// 2) jacW: blocks 0..511 = jaccard 128x64; blocks 512..575 = W2 = Wo@Wv.
//    Jaccard LDS v6: pitch-18-int4 rows (72 words = 8 mod 32, 16B-ALIGNED —
//    R4..R9's pitch-17 Ks made odd rows' int4 reads misaligned) + XOR group
//    placement [r][g^(r>>3)] (Q) / [r][g^(r>>2)] (K). Bank algebra: Q-reads
//    4 segs on 4 distinct bank-groups (conflict-free), K-reads 16 segs 2-way
//    (free, m136), all aligned.
// ---------------------------------------------------------------------------
union JacwSmem {
    struct {
        int Qs[128 * 72];                 // 36 KB  (pitch 18 int4)
        int Ks[64 * 72];                  // 18 KB
        float lut[K_HASH + 1];
    } jac;
    struct {
        ushort_t As[2][64 * 32];
        ushort_t Bs[2][64 * 32];
    } g;
};

__global__ __launch_bounds__(256) void jacw_kernel(
        const ushort_t* __restrict__ sigq, const ushort_t* __restrict__ sigk,
        ushort_t* __restrict__ P, float* __restrict__ rs,
        const ushort_t* __restrict__ Wob, const ushort_t* __restrict__ WvT,
        ushort_t* __restrict__ W2) {
    __shared__ JacwSmem sm;
    int blk = blockIdx.x, tid = threadIdx.x;
    if (blk >= 512) {                     // ---- W2[n,e] = sum_m Wo[n,m]Wv[m,e]
        int t = blk - 512;
        gemm64<0, EPI_NONE>(Wob, WvT, W2, nullptr, nullptr,
                            EDIM, EDIM, EDIM, EDIM,
                            (t >> 3) * 64, (t & 7) * 64,
                            sm.g.As[0], sm.g.Bs[0], tid);
        return;
    }
    // ---- jaccard 128x64: b = blk>>7, q0 = ((blk>>4)&7)*128, j0 = (blk&15)*64
    if (tid <= K_HASH) {
        float r = (float)(K_HASH - tid) / (float)(K_HASH + tid);
        sm.jac.lut[tid] = expf(expf(-GAMMA * (2.0f * S_SET) * r));
    }
    int b = blk >> 7;
    int q0 = ((blk >> 4) & 7) * 128, j0 = (blk & 15) * 64;
    const int4* gq = (const int4*)(sigq + ((size_t)b * LQ + q0) * K_HASH);
    const int4* gk = (const int4*)(sigk + ((size_t)b * LK + j0) * K_HASH);
    int r0 = tid >> 2, g0 = tid & 3;      // r0: 0..63
    int r1 = 64 + r0;
    #pragma unroll
    for (int ch = 0; ch < 4; ch++) {
        int g = ch * 4 + g0;
        *(int4*)&sm.jac.Qs[r0 * 72 + ((g ^ (r0 >> 3)) & 15) * 4] = gq[r0 * 16 + g];
        *(int4*)&sm.jac.Qs[r1 * 72 + ((g ^ (r1 >> 3)) & 15) * 4] = gq[r1 * 16 + g];
        *(int4*)&sm.jac.Ks[r0 * 72 + ((g ^ (r0 >> 2)) & 15) * 4] = gk[r0 * 16 + g];
    }
    __syncthreads();
    int tx = tid & 15, ty = tid >> 4;     // tx: 4 cols, ty: 8 rows per thread
    unsigned ones = 0x00010001u;
    unsigned acc[8][4] = {};
    #pragma unroll 1
    for (int ch = 0; ch < 4; ch++) {
        #pragma unroll
        for (int cc = 0; cc < 4; cc++) {
            int g = ch * 4 + cc;
            int qx = ((g ^ ty) & 15) * 4, kx = ((g ^ tx) & 15) * 4;
            int4 qv[8], kv[4];
            #pragma unroll
            for (int i = 0; i < 8; i++)
                qv[i] = *(const int4*)&sm.jac.Qs[(ty * 8 + i) * 72 + qx];
            #pragma unroll
            for (int j = 0; j < 4; j++)
                kv[j] = *(const int4*)&sm.jac.Ks[(tx * 4 + j) * 72 + kx];
            #pragma unroll
            for (int i = 0; i < 8; i++)
                #pragma unroll
                for (int j = 0; j < 4; j++)
                    acc[i][j] = nm8(acc[i][j], qv[i], kv[j], ones);
        }
    }
    // counts -> P (bf16) + per-row partial sums
    ushort_t* Pb = P + (size_t)b * LQ * LK;
    float fsum[8];
    #pragma unroll
    for (int i = 0; i < 8; i++) {
        ushort4 o;
        unsigned n0_ = (acc[i][0] & 0xFFFFu) + (acc[i][0] >> 16);
        unsigned n1_ = (acc[i][1] & 0xFFFFu) + (acc[i][1] >> 16);
        unsigned n2_ = (acc[i][2] & 0xFFFFu) + (acc[i][2] >> 16);
        unsigned n3_ = (acc[i][3] & 0xFFFFu) + (acc[i][3] >> 16);
        float p0 = sm.jac.lut[K_HASH - n0_], p1 = sm.jac.lut[K_HASH - n1_];
        float p2 = sm.jac.lut[K_HASH - n2_], p3 = sm.jac.lut[K_HASH - n3_];
        fsum[i] = (p0 + p1) + (p2 + p3);
        o.x = f2bf(p0); o.y = f2bf(p1); o.z = f2bf(p2); o.w = f2bf(p3);
        int row = q0 + ty * 8 + i;
        *(ushort4*)&Pb[(size_t)row * LK + j0 + tx * 4] = o;
    }
    __syncthreads();                      // reuse Qs as f32 scratch [128][16]
    float* fs = (float*)&sm.jac.Qs[0];
    #pragma unroll
    for (int i = 0; i < 8; i++) fs[(ty * 8 + i) * 16 + tx] = fsum[i];
    __syncthreads();
    if (tid < 128) {
        float s = 0.f;
        #pragma unroll
        for (int t = 0; t < 16; t++) s += fs[tid * 16 + t];
        atomicAdd(&rs[(size_t)b * LQ + q0 + tid], s);
    }
}

// ---------------------------------------------------------------------------
// 3) ctx2[bq,d] = sum_j P[bq,j] * value[b*1024+j, d]  (A=P, B=VbT rows).
//    1-D grid with XCD swizzle: id%8 = q0%8 constant across the 8 n-tiles
//    sharing a P row-block -> A-tile lives in ONE XCD's L2.
// ---------------------------------------------------------------------------
__global__ __launch_bounds__(256) void gemm_ctx2_kernel(
        const ushort_t* __restrict__ P, const ushort_t* __restrict__ VbT,
        ushort_t* __restrict__ ctx2) {
    __shared__ ushort_t As[2][64 * 32], Bs[2][64 * 32];
    int id = blockIdx.x;                  // 512
    int n0 = (id >> 6) * 64;              // 8 d-tiles
    int rem = id & 63;
    int z = rem >> 4;                     // 4 batches
    int q0 = (rem & 15) * 64;             // 16 q-tiles
    gemm64<0, EPI_NONE>(P + (size_t)z * LQ * LK, VbT + (size_t)z * LK,
                        ctx2 + (size_t)z * LQ * EDIM, nullptr, nullptr,
                        LK, NB * LK, EDIM, LK,
                        q0, n0, As[0], Bs[0], threadIdx.x);
}

// ---------------------------------------------------------------------------
// 4) out[bq,n] = ctx2[bq,:] . W2[n,:] / rs[bq] + bias2[n]   (f32 -> d_out)
// ---------------------------------------------------------------------------
__global__ __launch_bounds__(256) void gemm_out_kernel(
        const ushort_t* __restrict__ ctx2, const ushort_t* __restrict__ W2,
        float* __restrict__ out, const float* __restrict__ bias2,
        const float* __restrict__ rs) {
    __shared__ ushort_t As[2][64 * 32], Bs[2][64 * 32];
    gemm64<1, EPI_DIVBIAS>(ctx2, W2, out, bias2, rs,
                           EDIM, EDIM, EDIM, EDIM,
                           blockIdx.y * 64, blockIdx.x * 64,
                           As[0], Bs[0], threadIdx.x);
}

// ---------------------------------------------------------------------------
extern "C" void kernel_launch(void* const* d_in, const int* in_sizes, int n_in,
                              void* d_out, int out_size, void* d_ws, size_t ws_size,
                              hipStream_t stream) {
    // inputs: 0 query 1 key 2 value 3 ts_q 4 ts_k 5 ha 6 hb 7 Wq 8 bq 9 Wk 10 bk
    //         11 Wv 12 bv 13 Wo 14 bo   (q/k projections are dead code;
    //         Wv/Wo folded into W2 = Wo@Wv since all heads share one attn)
    const float* value = (const float*)d_in[2];
    const int* tsq = (const int*)d_in[3];
    const int* tsk = (const int*)d_in[4];
    const int* ha  = (const int*)d_in[5];
    const int* hb  = (const int*)d_in[6];
    const float* Wv = (const float*)d_in[11];
    const float* bv = (const float*)d_in[12];
    const float* Wo = (const float*)d_in[13];
    const float* bo = (const float*)d_in[14];
    float* out = (float*)d_out;

    char* ws = (char*)d_ws;
    ushort_t* sigq  = (ushort_t*)(ws);                         // 1 MB
    ushort_t* sigk  = (ushort_t*)(ws + (1ull << 20));          // 1 MB
    float*    rs    = (float*)(ws + (2ull << 20));             // 16 KB
    float*    bias2 = (float*)(ws + (2ull << 20) + (64 << 10)); // 2 KB
    ushort_t* P     = (ushort_t*)(ws + (4ull << 20));          // 8 MB
    ushort_t* VbT   = (ushort_t*)(ws + (12ull << 20));         // 4 MB [512 x 4096]
    ushort_t* ctx2  = (ushort_t*)(ws + (16ull << 20));         // 4 MB [4096 x 512]
    ushort_t* Wob   = (ushort_t*)(ws + (20ull << 20));         // 512 KB
    ushort_t* WvT   = (ushort_t*)(ws + (20ull << 20) + (512 << 10)); // 512 KB
    ushort_t* W2    = (ushort_t*)(ws + (21ull << 20));         // 512 KB [n x e]

    // 1) converts (Wo plain, value/Wv transposed) + signatures + bias2 + rs=0
    prep_kernel<<<PREP_BLOCKS, 256, 0, stream>>>(
        value, Wv, Wo, bv, bo, tsq, tsk, ha, hb,
        VbT, WvT, Wob, sigq, sigk, rs, bias2);

    // 2) P = exp(score) + rowsums (512 blocks); W2 = Wo@Wv (64 extra blocks)
    jacw_kernel<<<512 + 64, 256, 0, stream>>>(sigq, sigk, P, rs, Wob, WvT, W2);

    // 3) ctx2 = P @ value   (512 blocks, XCD-swizzled 1-D grid)
    gemm_ctx2_kernel<<<512, 256, 0, stream>>>(P, VbT, ctx2);

    // 4) out = (ctx2/rs) @ W2^T + bias2   (512 blocks, f32)
    gemm_out_kernel<<<dim3(EDIM / 64, NB * LQ / 64, 1), 256, 0, stream>>>(
        ctx2, W2, out, bias2, rs);
}

// Round 11
// 154.781 us; speedup vs baseline: 1.0910x; 1.0910x over previous
//
#include <hip/hip_runtime.h>
#include <hip/hip_bf16.h>
#include <stdint.h>

// Problem constants (fixed by setup_inputs)
#define PRIME 2147483647u
#define GAMMA 0.3f
#define K_HASH 128
#define S_SET 8
#define NB 4
#define LQ 1024
#define LK 1024
#define EDIM 512

typedef unsigned short ushort_t;
typedef __attribute__((ext_vector_type(8))) short short8;
typedef __attribute__((ext_vector_type(4))) float f32x4;

static __device__ __forceinline__ unsigned short f2bf(float f) {
    unsigned u = __builtin_bit_cast(unsigned, f);
    u += 0x7FFFu + ((u >> 16) & 1u);   // RNE (no NaN in this problem)
    return (unsigned short)(u >> 16);
}

// async global->LDS, 16B per lane; LDS dst must be lane-contiguous.
static __device__ __forceinline__ void glds16(const void* g, void* l) {
    __builtin_amdgcn_global_load_lds(
        (const __attribute__((address_space(1))) unsigned int*)g,
        (__attribute__((address_space(3))) unsigned int*)l, 16, 0, 0);
}

#define SWZ(r) ((((r) >> 2) & 3) ^ ((r) & 3))

// packed nonmatch accumulate: acc += per-half min(a^b,1). Forced v_pk_min_u16
// (LLVM scalarizes __builtin_elementwise_min on u16x2: R5->R6 proved 2.1x).
static __device__ __forceinline__ unsigned nm2(unsigned acc, unsigned a,
                                               unsigned b, unsigned ones) {
    unsigned x = a ^ b, t;
    asm("v_pk_min_u16 %0, %1, %2" : "=v"(t) : "v"(x), "v"(ones));
    return acc + t;                       // halves <= 64: no cross-half carry
}
static __device__ __forceinline__ unsigned nm8(unsigned acc, int4 q, int4 k,
                                               unsigned ones) {
    acc = nm2(acc, (unsigned)q.x, (unsigned)k.x, ones);
    acc = nm2(acc, (unsigned)q.y, (unsigned)k.y, ones);
    acc = nm2(acc, (unsigned)q.z, (unsigned)k.z, ones);
    acc = nm2(acc, (unsigned)q.w, (unsigned)k.w, ones);
    return acc;
}

// ---------------------------------------------------------------------------
// 1) prep: fused f32->bf16 convert (value/Wv/Wo) + MinHash signatures.
//    Signatures truncated to low 16 bits (FP rate 2^-16, output effect ~1e-6).
// ---------------------------------------------------------------------------
#define CVT_N0 (NB * LK * EDIM)
#define CVT_N1 (EDIM * EDIM)
#define CVT_N2 (EDIM * EDIM)
#define CVT_BLOCKS ((CVT_N0 + CVT_N1 + CVT_N2) / (256 * 8))   // 1280
#define SIG_BLOCKS (NB * (LQ + LK) / 2)                        // 4096 (2 rows/blk)

__global__ __launch_bounds__(256) void prep_kernel(
        const float* __restrict__ v, const float* __restrict__ wv,
        const float* __restrict__ wo,
        ushort_t* __restrict__ vb, ushort_t* __restrict__ wvb,
        ushort_t* __restrict__ wob,
        const int* __restrict__ ts_q, const int* __restrict__ ts_k,
        const int* __restrict__ ha, const int* __restrict__ hb,
        ushort_t* __restrict__ sig_q, ushort_t* __restrict__ sig_k,
        float* __restrict__ rs) {
    int blk = blockIdx.x;
    if (blk < CVT_BLOCKS) {               // ---- convert branch ----
        size_t i = ((size_t)blk * 256 + threadIdx.x) * 8;
        const float* src; ushort_t* dst; size_t off;
        if (i < CVT_N0)                { src = v;  dst = vb;  off = i; }
        else if (i < CVT_N0 + CVT_N1)  { src = wv; dst = wvb; off = i - CVT_N0; }
        else                           { src = wo; dst = wob; off = i - CVT_N0 - CVT_N1; }
        float4 a = *(const float4*)(src + off);
        float4 b = *(const float4*)(src + off + 4);
        ushort4 o0, o1;
        o0.x = f2bf(a.x); o0.y = f2bf(a.y); o0.z = f2bf(a.z); o0.w = f2bf(a.w);
        o1.x = f2bf(b.x); o1.y = f2bf(b.y); o1.z = f2bf(b.z); o1.w = f2bf(b.w);
        *(ushort4*)(dst + off)     = o0;
        *(ushort4*)(dst + off + 4) = o1;
        return;
    }
    // ---- signature branch: 2 token-sets per block (128 threads each) ----
    int sb = blk - CVT_BLOCKS;            // 0..4095
    if (sb < 16) rs[sb * 256 + threadIdx.x] = 0.f;  // zero rowsum[4096]
    int half = threadIdx.x >> 7, k = threadIdx.x & 127;
    int row = sb * 2 + half;              // 0..8191 (halves never straddle 4096)
    const int* ts = (row < NB * LQ) ? ts_q : ts_k;
    ushort_t* sig = (row < NB * LQ) ? sig_q : sig_k;
    int idx = row & (NB * LQ - 1);
    unsigned long long a  = (unsigned)ha[k];
    unsigned long long bb = (unsigned)hb[k];
    __shared__ int ids[2][S_SET];
    if (k < S_SET) ids[half][k] = ts[idx * S_SET + k];
    __syncthreads();
    unsigned mn = 0xFFFFFFFFu;
    #pragma unroll
    for (int s = 0; s < S_SET; s++) {
        unsigned long long x = a * (unsigned long long)(unsigned)ids[half][s] + bb;
        x = (x & PRIME) + (x >> 31);      // 2^31 == 1 (mod 2^31-1)
        x = (x & PRIME) + (x >> 31);
        unsigned r = (unsigned)x;
        if (r >= PRIME) r -= PRIME;
        mn = (r < mn) ? r : mn;
    }
    sig[idx * K_HASH + k] = (ushort_t)mn;
}

// ---------------------------------------------------------------------------
// 2) Jaccard v7: 64x64 tile, 1024 blocks (4 blocks/CU, 4 waves/SIMD), 4x4
//    per thread. K staged in TWO HALVES of 8 int4-groups -> LDS 18.9 KB so
//    occupancy is grid-bound not LDS-bound. Pitch 36 words/row: every
//    ds_read_b128 16B-ALIGNED (pitch-17 of R4..R9 misaligned odd rows).
//    XOR placement [r][(g^(r>>2))&7]: Q-reads broadcast/conflict-free,
//    K-reads exactly 2-way (free, m136).
// ---------------------------------------------------------------------------
__global__ __launch_bounds__(256) void jaccard_kernel(
        const ushort_t* __restrict__ sig_q, const ushort_t* __restrict__ sig_k,
        ushort_t* __restrict__ P, float* __restrict__ rs) {
    __shared__ int Qs[64 * 36];           // 9 KB (pitch 9 int4)
    __shared__ int Ks[64 * 36];           // 9 KB
    __shared__ float lut[K_HASH + 1];
    int tid = threadIdx.x;
    if (tid <= K_HASH) {
        float r = (float)(K_HASH - tid) / (float)(K_HASH + tid); // (1-J)/(1+J)
        lut[tid] = expf(expf(-GAMMA * (2.0f * S_SET) * r));      // softmax numer
    }
    int b = blockIdx.z;
    int q0 = blockIdx.y * 64, j0 = blockIdx.x * 64;
    const int4* gq = (const int4*)(sig_q + ((size_t)b * LQ + q0) * K_HASH);
    const int4* gk = (const int4*)(sig_k + ((size_t)b * LK + j0) * K_HASH);
    int tx = tid & 15, ty = tid >> 4;     // 4 cols x 4 rows per thread
    unsigned ones = 0x00010001u;
    unsigned acc[4][4] = {};
    int sr = tid >> 2, sg0 = (tid & 3) * 2;   // staging: 2 int4 each for Q and K
    #pragma unroll 1
    for (int h = 0; h < 2; h++) {         // two halves of 8 hash-groups
        __syncthreads();                  // previous half fully consumed
        #pragma unroll
        for (int u = 0; u < 2; u++) {
            int g = sg0 + u;
            *(int4*)&Qs[sr * 36 + ((g ^ (sr >> 2)) & 7) * 4] = gq[sr * 16 + h * 8 + g];
            *(int4*)&Ks[sr * 36 + ((g ^ (sr >> 2)) & 7) * 4] = gk[sr * 16 + h * 8 + g];
        }
        __syncthreads();
        #pragma unroll
        for (int g = 0; g < 8; g++) {
            int qx = ((g ^ ty) & 7) * 4, kx = ((g ^ tx) & 7) * 4;
            int4 qv[4], kv[4];
            #pragma unroll
            for (int i = 0; i < 4; i++)
                qv[i] = *(const int4*)&Qs[(ty * 4 + i) * 36 + qx];
            #pragma unroll
            for (int j = 0; j < 4; j++)
                kv[j] = *(const int4*)&Ks[(tx * 4 + j) * 36 + kx];
            #pragma unroll
            for (int i = 0; i < 4; i++)
                #pragma unroll
                for (int j = 0; j < 4; j++)
                    acc[i][j] = nm8(acc[i][j], qv[i], kv[j], ones);
        }
    }
    // counts -> P (bf16) + per-row partial sums
    ushort_t* Pb = P + (size_t)b * LQ * LK;
    float fsum[4];
    #pragma unroll
    for (int i = 0; i < 4; i++) {
        ushort4 o;
        unsigned n0_ = (acc[i][0] & 0xFFFFu) + (acc[i][0] >> 16);
        unsigned n1_ = (acc[i][1] & 0xFFFFu) + (acc[i][1] >> 16);
        unsigned n2_ = (acc[i][2] & 0xFFFFu) + (acc[i][2] >> 16);
        unsigned n3_ = (acc[i][3] & 0xFFFFu) + (acc[i][3] >> 16);
        float p0 = lut[K_HASH - n0_], p1 = lut[K_HASH - n1_];
        float p2 = lut[K_HASH - n2_], p3 = lut[K_HASH - n3_];
        fsum[i] = (p0 + p1) + (p2 + p3);
        o.x = f2bf(p0); o.y = f2bf(p1); o.z = f2bf(p2); o.w = f2bf(p3);
        int row = q0 + ty * 4 + i;
        *(ushort4*)&Pb[(size_t)row * LK + j0 + tx * 4] = o;
    }
    __syncthreads();                      // compute done; reuse Qs as f32 scratch
    float* fs = (float*)&Qs[0];           // [64 rows][16 tx]
    #pragma unroll
    for (int i = 0; i < 4; i++) fs[(ty * 4 + i) * 16 + tx] = fsum[i];
    __syncthreads();
    if (tid < 64) {
        float s = 0.f;
        #pragma unroll
        for (int t = 0; t < 16; t++) s += fs[tid * 16 + t];
        atomicAdd(&rs[(size_t)b * LQ + q0 + tid], s);
    }
}

// ---------------------------------------------------------------------------
// 4) bf16 BT-GEMM: C[M,N] = A[M,K] @ B[N,K]^T (+epilogue), f32 accum.
//    64x64 tile, 256 thr (4 waves x 32x32), glds width-16, XOR-swizzled LDS,
//    double-buffered. 512+-block grids -> >=2 waves/SIMD.
// ---------------------------------------------------------------------------
#define EPI_ROWBIAS  0
#define EPI_ROWDIV   1
#define EPI_COLBIAS  2

template<int OUTF32, int MODE>
__global__ __launch_bounds__(256) void btgemm_kernel(
        const ushort_t* __restrict__ A, const ushort_t* __restrict__ B,
        void* __restrict__ C,
        const float* __restrict__ bias, const float* __restrict__ scale,
        int lda, int ldb, int ldc, int Kd,
        long long sA, long long sB, long long sC, long long sS) {
    __shared__ ushort_t As[2][64 * 32];   // 4 KB x2
    __shared__ ushort_t Bs[2][64 * 32];   // 4 KB x2
    int z = blockIdx.z;
    int m0 = blockIdx.y * 64, n0 = blockIdx.x * 64;
    int tid = threadIdx.x;
    int w = tid >> 6, lane = tid & 63;
    int wm = (w & 1) * 32, wn = (w >> 1) * 32;
    int mrow = lane & 15, kg = lane >> 4;

    int r = tid >> 2, c = (tid & 3) ^ SWZ(r);
    const ushort_t* pa = A + (size_t)z * sA + (size_t)(m0 + r) * lda + c * 8;
    const ushort_t* pb = B + (size_t)z * sB + (size_t)(n0 + r) * ldb + c * 8;

    int aoff[2], boff[2];
    #pragma unroll
    for (int s = 0; s < 2; s++) {
        int Ra = wm + s * 16 + mrow;
        aoff[s] = Ra * 32 + (kg ^ SWZ(Ra)) * 8;
        int Rb = wn + s * 16 + mrow;
        boff[s] = Rb * 32 + (kg ^ SWZ(Rb)) * 8;
    }

    f32x4 acc[2][2] = {};
    int nK = Kd >> 5;
    glds16(pa, &As[0][tid * 8]);
    glds16(pb, &Bs[0][tid * 8]);
    for (int i = 0; i < nK; i++) {
        __syncthreads();
        int cur = i & 1, nxt = cur ^ 1;
        if (i + 1 < nK) {
            int k0 = (i + 1) << 5;
            glds16(pa + k0, &As[nxt][tid * 8]);
            glds16(pb + k0, &Bs[nxt][tid * 8]);
        }
        short8 af[2], bh[2];
        #pragma unroll
        for (int s = 0; s < 2; s++) {
            af[s] = *(const short8*)&As[cur][aoff[s]];
            bh[s] = *(const short8*)&Bs[cur][boff[s]];
        }
        #pragma unroll
        for (int ii = 0; ii < 2; ii++)
            #pragma unroll
            for (int jj = 0; jj < 2; jj++)
                acc[ii][jj] = __builtin_amdgcn_mfma_f32_16x16x32_bf16(
                                  af[ii], bh[jj], acc[ii][jj], 0, 0, 0);
    }

    const float* sc = scale + (size_t)z * sS;
    int col = lane & 15, rbase = (lane >> 4) * 4;
    #pragma unroll
    for (int ii = 0; ii < 2; ii++) {
        #pragma unroll
        for (int jj = 0; jj < 2; jj++) {
            #pragma unroll
            for (int rr = 0; rr < 4; rr++) {
                int gm = m0 + wm + ii * 16 + rbase + rr;
                int gn = n0 + wn + jj * 16 + col;
                float v = acc[ii][jj][rr];
                if (MODE == EPI_ROWBIAS)     v += bias[gm];
                else if (MODE == EPI_ROWDIV) v /= sc[gm];
                else                         v += bias[gn];
                size_t cix = (size_t)z * sC + (size_t)gm * ldc + gn;
                if (OUTF32) ((float*)C)[cix] = v;
                else        ((ushort_t*)C)[cix] = f2bf(v);
            }
        }
    }
}

// ---------------------------------------------------------------------------
extern "C" void kernel_launch(void* const* d_in, const int* in_sizes, int n_in,
                              void* d_out, int out_size, void* d_ws, size_t ws_size,
                              hipStream_t stream) {
    // inputs: 0 query 1 key 2 value 3 ts_q 4 ts_k 5 ha 6 hb 7 Wq 8 bq 9 Wk 10 bk
    //         11 Wv 12 bv 13 Wo 14 bo   (q/k projections are dead code)
    const float* value = (const float*)d_in[2];
    const int* tsq = (const int*)d_in[3];
    const int* tsk = (const int*)d_in[4];
    const int* ha  = (const int*)d_in[5];
    const int* hb  = (const int*)d_in[6];
    const float* Wv = (const float*)d_in[11];
    const float* bv = (const float*)d_in[12];
    const float* Wo = (const float*)d_in[13];
    const float* bo = (const float*)d_in[14];
    float* out = (float*)d_out;

    char* ws = (char*)d_ws;
    ushort_t* sigq   = (ushort_t*)(ws);                              // 1 MB
    ushort_t* sigk   = (ushort_t*)(ws + (1ull << 20));               // 1 MB
    ushort_t* P      = (ushort_t*)(ws + (4ull << 20));               // 8 MB
    float* rs        = (float*)(ws + (12ull << 20));                 // 16 KB
    ushort_t* Vt     = (ushort_t*)(ws + (12ull << 20) + (1ull << 16)); // 4 MB [512 x 4096]
    ushort_t* ctx    = (ushort_t*)(ws + (17ull << 20));              // 4 MB [4096 x 512]
    ushort_t* Vb     = (ushort_t*)(ws + (21ull << 20));              // 4 MB [4096 x 512]
    ushort_t* Wvb    = (ushort_t*)(ws + (25ull << 20));              // 512 KB
    ushort_t* Wob    = (ushort_t*)(ws + (25ull << 20) + (512ull << 10)); // 512 KB

    // 1) fused convert + signatures (+ zero rs)
    prep_kernel<<<CVT_BLOCKS + SIG_BLOCKS, 256, 0, stream>>>(
        value, Wv, Wo, Vb, Wvb, Wob, tsq, tsk, ha, hb, sigq, sigk, rs);

    // 2) P = exp(score) (bf16) + row sums into rs  (1024 blocks, 4/CU)
    jaccard_kernel<<<dim3(LK / 64, LQ / 64, NB), 256, 0, stream>>>(sigq, sigk, P, rs);

    // 4) Vt[d, b*1024+j] = sum_e Wvb[d,e]*Vb[b*1024+j, e] + bv[d]
    btgemm_kernel<0, EPI_ROWBIAS><<<dim3(4096 / 64, 512 / 64, 1), 256, 0, stream>>>(
        Wvb, Vb, Vt, bv, rs /*unused*/,
        EDIM, EDIM, NB * LK, EDIM, 0LL, 0LL, 0LL, 0LL);

    // 5) ctx[b*1024+q, d] = (1/rs[b,q]) * sum_j P[b,q,j]*Vt[d, b*1024+j]
    btgemm_kernel<0, EPI_ROWDIV><<<dim3(EDIM / 64, LQ / 64, NB), 256, 0, stream>>>(
        P, Vt, ctx, bv /*unused*/, rs,
        LK, NB * LK, EDIM, LK,
        (long long)LQ * LK, (long long)LK, (long long)LQ * EDIM, (long long)LQ);

    // 6) out[bq, n] = sum_e ctx[bq,e]*Wob[n,e] + bo[n]  (f32 -> d_out)
    btgemm_kernel<1, EPI_COLBIAS><<<dim3(EDIM / 64, NB * LQ / 64, 1), 256, 0, stream>>>(
        ctx, Wob, out, bo, rs /*unused*/,
        EDIM, EDIM, EDIM, EDIM, 0LL, 0LL, 0LL, 0LL);
}